// Round 10
// baseline (2169.459 us; speedup 1.0000x reference)
//
#include <hip/hip_runtime.h>
#include <hip/hip_bf16.h>

#define Vn 25000
#define En 100000
#define NODE_IN 74
#define EDGE_IN 12
#define OUTD 64
#define EHID 128
#define NUM_STEPS 6

typedef __attribute__((ext_vector_type(8))) _Float16 half8;
typedef __attribute__((ext_vector_type(4))) _Float16 half4;
typedef __attribute__((ext_vector_type(4))) float floatx4;

// h[v,o] = relu(node[v,:] @ Wp + bp)   [V,74]@[74,64]  (all fp32)
__global__ void proj_kernel(const float* __restrict__ node,
                            const float* __restrict__ Wp,
                            const float* __restrict__ bp,
                            float* __restrict__ h) {
  __shared__ float nf[NODE_IN];
  int v = blockIdx.x;
  int o = threadIdx.x;  // 64
  for (int i = o; i < NODE_IN; i += 64) nf[i] = node[(size_t)v * NODE_IN + i];
  __syncthreads();
  float acc = bp[o];
  for (int i = 0; i < NODE_IN; ++i) acc = fmaf(nf[i], Wp[i * OUTD + o], acc);
  h[(size_t)v * OUTD + o] = fmaxf(acc, 0.0f);
}

// f[e,k] = relu(edge[e,:] @ We1 + be1)   [E,12]@[12,128] fp32, stored f16
__global__ void edge_kernel(const float* __restrict__ ef,
                            const float* __restrict__ We1,
                            const float* __restrict__ be1,
                            _Float16* __restrict__ f) {
  __shared__ float es[EDGE_IN];
  int e = blockIdx.x;
  int k = threadIdx.x;  // 128
  if (k < EDGE_IN) es[k] = ef[(size_t)e * EDGE_IN + k];
  __syncthreads();
  float acc = be1[k];
  for (int j = 0; j < EDGE_IN; ++j) acc = fmaf(es[j], We1[j * EHID + k], acc);
  f[(size_t)e * EHID + k] = (_Float16)fmaxf(acc, 0.0f);
}

// SSTEP-contiguous + bank-swizzled B layout (f16) — unchanged from r7-r9.
// Logical index: g = step*2048 + c*512 + l15*32 + quad*8 + j, step = i*4+s,
// value = f16(We2[k = s*32+quad*8+j][col = i*64 + c*16 + l15]).
// Stored at step*2048 + (eidx ^ ((eidx>>6 & 3) << 3))  (quad ^= l15[2:1]).
__global__ void w2r_kernel(const float* __restrict__ We2,
                           _Float16* __restrict__ w2s) {
  int g = blockIdx.x * 256 + threadIdx.x;  // < 524288 (logical index)
  int j = g & 7;
  int quad = (g >> 3) & 3;
  int l15 = (g >> 5) & 15;
  int c = (g >> 9) & 3;
  int step = g >> 11;     // 0..255
  int s = step & 3;
  int i = step >> 2;
  int k = s * 32 + quad * 8 + j;
  int col = i * 64 + c * 16 + l15;
  int eidx = g & 2047;
  int estore = eidx ^ (((eidx >> 6) & 3) << 3);
  w2s[((size_t)step << 11) | estore] = (_Float16)We2[(size_t)k * (OUTD * OUTD) + col];
}

#define GLOAD_LDS(gp, lp)                                                     \
  __builtin_amdgcn_global_load_lds(                                           \
      (const __attribute__((address_space(1))) void*)(gp),                    \
      (__attribute__((address_space(3))) void*)(lp), 16, 0, 0)

// Fused per-step message kernel: one wave per (64-edge tile, i-HALF).
// blockIdx -> tile = bid>>1, ihalf = bid&1 handling i in [32*ihalf, +32).
// Grid 3126 single-wave blocks = 12.2 waves/CU (3/SIMD) — fixes r9's
// grid-capped occupancy (6.1 waves/CU). Each wave: 128 KSTEPs, full
// [64e][64o] partial in acc, direct atomic scatter (2 atomics/output from
// the two i-halves). LDS/block 12.5KB. KSTEP pipeline identical to r9
// (proven race-free): lgkmcnt(0) drains slot reads before re-stage DMA;
// vmcnt(4) (in-order retirement) covers the chunk read this KSTEP.
__global__ __launch_bounds__(64, 4) void msg_kernel(
    const float* __restrict__ h,
    const _Float16* __restrict__ f,
    const _Float16* __restrict__ w2s,
    const int* __restrict__ src,
    const int* __restrict__ dst,
    const float* __restrict__ be2,
    float* __restrict__ agg) {
  // [0,4096): h16[32 li][64 e-permuted] f16; [4096,12288): 2-slot ring.
  __shared__ __align__(16) char smem_raw[12288];
  __shared__ int s_dst[64];

  _Float16* h16 = (_Float16*)smem_raw;  // elem (li, p): p = (e&15)*4 + (e>>4)
  char* ring = smem_raw + 4096;

  const int lane = threadIdx.x;
  const int quad = lane >> 4;
  const int l15 = lane & 15;
  const int tile = blockIdx.x >> 1;
  const int ihalf = blockIdx.x & 1;
  const int e0 = tile * 64;
  const int SBASE = ihalf * 128;        // first w2s step of this wave
  const int SMAX = SBASE + 127;         // last valid step

  // dst + h-gather for this wave's i-half (lane e owns edge e0+e).
  // Permuted store: p(e) = (e&15)*4 + (e>>4) so a reader lane's 4 t-values
  // (e = t*16+l15, t=0..3) are contiguous 8B -> one ds_read_b64.
  {
    int eg = e0 + lane;
    s_dst[lane] = (eg < En) ? dst[eg] : -1;
    int sv = (eg < En) ? src[eg] : 0;
    const float4* hp = reinterpret_cast<const float4*>(h + (size_t)sv * OUTD + ihalf * 32);
    int pe = (l15 << 2) + quad;
#pragma unroll
    for (int c = 0; c < 8; ++c) {
      float4 v = hp[c];
      int li = c * 4;
      h16[(li + 0) * 64 + pe] = (_Float16)v.x;
      h16[(li + 1) * 64 + pe] = (_Float16)v.y;
      h16[(li + 2) * 64 + pe] = (_Float16)v.z;
      h16[(li + 3) * 64 + pe] = (_Float16)v.w;
    }
  }

  // A-fragments (f16): F rows for 4 row-tiles x 4 K-steps (i-invariant).
  half8 afr[4][4];
#pragma unroll
  for (int t = 0; t < 4; ++t) {
    int e = e0 + t * 16 + l15;
    if (e >= En) e = En - 1;  // clamped rows suppressed at scatter
    const _Float16* fr = f + (size_t)e * EHID + quad * 8;
#pragma unroll
    for (int s = 0; s < 4; ++s)
      afr[t][s] = *reinterpret_cast<const half8*>(fr + s * 32);
  }

  floatx4 acc[4][4];  // [row-tile t][col-stripe c] — this i-half's sum
  const floatx4 zero4 = (floatx4){0.f, 0.f, 0.f, 0.f};
#pragma unroll
  for (int t = 0; t < 4; ++t)
#pragma unroll
    for (int c = 0; c < 4; ++c) acc[t][c] = zero4;

  const char* w2b = (const char*)w2s;
  // swizzled per-lane byte offset within a 4KB chunk (stripe c adds 1024)
  const int roff = l15 * 64 + ((quad ^ ((l15 >> 1) & 3)) << 4);
  const char* sp0 = ring + roff;
  const char* sp1 = ring + 4096 + roff;

#define STAGE(GS, SLOT)                                                       \
  {                                                                           \
    const char* gp_ = w2b + (size_t)(GS) * 4096 + lane * 16;                  \
    char* lp_ = ring + (SLOT) * 4096;                                         \
    GLOAD_LDS(gp_, lp_);                                                      \
    GLOAD_LDS(gp_ + 1024, lp_ + 1024);                                        \
    GLOAD_LDS(gp_ + 2048, lp_ + 2048);                                        \
    GLOAD_LDS(gp_ + 3072, lp_ + 3072);                                        \
  }

#define VM4 asm volatile("s_waitcnt vmcnt(4)" ::: "memory")
#define LGKM0 asm volatile("s_waitcnt lgkmcnt(0)" ::: "memory")
#define SB __builtin_amdgcn_sched_barrier(0)

// KSTEP: (1) LGKM0 drains last KSTEP's ds_reads so the re-stage DMA can't
// race them; (2) stage step GST (clamped; tail reloads are never consumed)
// into the slot whose data (BMM) is already in registers; (3) vmcnt(4):
// in-order retirement => the chunk read now (staged one KSTEP ago) landed;
// (4) read next chunk -> BRD; (5) 16 MFMA on BMM under setprio(1).
#define KSTEP(SS, BMM, BRD, STSLOT, RDP, GST)                                 \
  {                                                                           \
    LGKM0;                                                                    \
    SB;                                                                       \
    int gs_ = (GST) > SMAX ? SMAX : (GST);                                    \
    STAGE(gs_, STSLOT);                                                       \
    VM4;                                                                      \
    BRD[0] = *reinterpret_cast<const half8*>(RDP);                            \
    BRD[1] = *reinterpret_cast<const half8*>(RDP + 1024);                     \
    BRD[2] = *reinterpret_cast<const half8*>(RDP + 2048);                     \
    BRD[3] = *reinterpret_cast<const half8*>(RDP + 3072);                     \
    __builtin_amdgcn_s_setprio(1);                                            \
    _Pragma("unroll") for (int t = 0; t < 4; ++t) {                           \
      half8 as = afr[t][SS] * hb[t];                                          \
      acc[t][0] = __builtin_amdgcn_mfma_f32_16x16x32_f16(as, BMM[0], acc[t][0], 0, 0, 0); \
      acc[t][1] = __builtin_amdgcn_mfma_f32_16x16x32_f16(as, BMM[1], acc[t][1], 0, 0, 0); \
      acc[t][2] = __builtin_amdgcn_mfma_f32_16x16x32_f16(as, BMM[2], acc[t][2], 0, 0, 0); \
      acc[t][3] = __builtin_amdgcn_mfma_f32_16x16x32_f16(as, BMM[3], acc[t][3], 0, 0, 0); \
    }                                                                         \
    __builtin_amdgcn_s_setprio(0);                                            \
  }

  // prologue: stage local steps 0,1; wait step 0 landed; read it into P
  STAGE(SBASE, 0);
  STAGE(SBASE + 1, 1);
  VM4;
  half8 P[4], Q[4];
  P[0] = *reinterpret_cast<const half8*>(sp0);
  P[1] = *reinterpret_cast<const half8*>(sp0 + 1024);
  P[2] = *reinterpret_cast<const half8*>(sp0 + 2048);
  P[3] = *reinterpret_cast<const half8*>(sp0 + 3072);

  for (int li = 0; li < 32; ++li) {
    // hb[t] = h(i = 32*ihalf + li, edge e = t*16+l15): one ds_read_b64
    half4 hv = *reinterpret_cast<const half4*>(h16 + li * 64 + l15 * 4);
    half8 hb[4];
#pragma unroll
    for (int t = 0; t < 4; ++t) {
      _Float16 hf = hv[t];
      hb[t] = (half8){hf, hf, hf, hf, hf, hf, hf, hf};
    }
    int gs = SBASE + li * 4;
    // slots: step parity; P/Q alternate. Invariant entering li: P = B(gs).
    KSTEP(0, P, Q, 0, sp1, gs + 2);
    KSTEP(1, Q, P, 1, sp0, gs + 3);
    KSTEP(2, P, Q, 0, sp1, gs + 4);
    KSTEP(3, Q, P, 1, sp0, gs + 5);
  }

  // be2 contribution (exact 0 here, kept for generality): this wave adds
  // only its own i-half K-chunk (s = ihalf), so the tile pair sums the full
  // sum_i h[e,i]*be2[i*64+o] exactly once.
  {
    half8 b2f[4];
#pragma unroll
    for (int c = 0; c < 4; ++c) {
      half8 v;
#pragma unroll
      for (int j = 0; j < 8; ++j)
        v[j] = (_Float16)be2[(ihalf * 32 + quad * 8 + j) * 64 + c * 16 + l15];
      b2f[c] = v;
    }
#pragma unroll
    for (int t = 0; t < 4; ++t) {
      half8 ha;
#pragma unroll
      for (int j = 0; j < 8; ++j)
        ha[j] = h16[(quad * 8 + j) * 64 + l15 * 4 + t];
#pragma unroll
      for (int c = 0; c < 4; ++c)
        acc[t][c] = __builtin_amdgcn_mfma_f32_16x16x32_f16(ha, b2f[c], acc[t][c], 0, 0, 0);
    }
  }

  // direct scatter (partial sums; 2 atomics/output across the i-half pair).
  // C/D layout col=lane&15, row=quad*4+reg (within each 16-row tile).
#pragma unroll
  for (int t = 0; t < 4; ++t) {
    int rb = t * 16 + quad * 4;
#pragma unroll
    for (int c = 0; c < 4; ++c) {
      int col = c * 16 + l15;
#pragma unroll
      for (int r = 0; r < 4; ++r) {
        int d = s_dst[rb + r];
        if (d >= 0) atomicAdd(&agg[(size_t)d * OUTD + col], acc[t][c][r]);
      }
    }
  }
}

// h_out = relu(agg + bias); re-zero agg; last step also writes fp32 d_out
__global__ void update_kernel(float* __restrict__ agg,
                              const float* __restrict__ bias,
                              float* __restrict__ hout,
                              float* __restrict__ dout, int last) {
  int g = blockIdx.x * 256 + threadIdx.x;
  if (g >= Vn * OUTD) return;
  float v = agg[g];
  agg[g] = 0.0f;
  float r = fmaxf(v + bias[g & 63], 0.0f);
  hout[g] = r;
  if (last) dout[g] = r;
}

extern "C" void kernel_launch(void* const* d_in, const int* in_sizes, int n_in,
                              void* d_out, int out_size, void* d_ws, size_t ws_size,
                              hipStream_t stream) {
  const float* node = (const float*)d_in[0];
  const float* edge = (const float*)d_in[1];
  const int* src = (const int*)d_in[2];
  const int* dst = (const int*)d_in[3];
  const float* Wp   = (const float*)d_in[4];
  const float* bp   = (const float*)d_in[5];
  const float* We1  = (const float*)d_in[6];
  const float* be1  = (const float*)d_in[7];
  const float* We2  = (const float*)d_in[8];
  const float* be2  = (const float*)d_in[9];
  const float* bias = (const float*)d_in[10];
  float* out = (float*)d_out;

  char* ws = (char*)d_ws;
  float* agg = (float*)(ws);                        // 6,400,000 B
  float* h_a = (float*)(ws + 6400000);              // 6,400,000 B
  float* h_b = (float*)(ws + 12800000);             // 6,400,000 B
  _Float16* f   = (_Float16*)(ws + 19200000);       // 25,600,000 B
  _Float16* w2s = (_Float16*)(ws + 44800000);       // 1,048,576 B

  hipMemsetAsync(agg, 0, (size_t)Vn * OUTD * sizeof(float), stream);
  proj_kernel<<<Vn, 64, 0, stream>>>(node, Wp, bp, h_a);
  edge_kernel<<<En, 128, 0, stream>>>(edge, We1, be1, f);
  w2r_kernel<<<(OUTD * OUTD * EHID) / 256, 256, 0, stream>>>(We2, w2s);

  float* hin = h_a;
  float* hout = h_b;
  const int ntiles = (En + 63) / 64;  // 1563
  for (int s = 0; s < NUM_STEPS; ++s) {
    msg_kernel<<<ntiles * 2, 64, 0, stream>>>(hin, f, w2s, src, dst, be2, agg);
    update_kernel<<<(Vn * OUTD + 255) / 256, 256, 0, stream>>>(
        agg, bias, hout, out, s == NUM_STEPS - 1);
    float* t = hin; hin = hout; hout = t;
  }
}

// Round 11
// 883.405 us; speedup vs baseline: 2.4558x; 2.4558x over previous
//
#include <hip/hip_runtime.h>
#include <hip/hip_bf16.h>

#define Vn 25000
#define En 100000
#define NODE_IN 74
#define EDGE_IN 12
#define OUTD 64
#define EHID 128
#define NUM_STEPS 6

typedef __attribute__((ext_vector_type(8))) _Float16 half8;
typedef __attribute__((ext_vector_type(4))) _Float16 half4;
typedef __attribute__((ext_vector_type(4))) float floatx4;

// h[v,o] = relu(node[v,:] @ Wp + bp)   [V,74]@[74,64]  (all fp32)
__global__ void proj_kernel(const float* __restrict__ node,
                            const float* __restrict__ Wp,
                            const float* __restrict__ bp,
                            float* __restrict__ h) {
  __shared__ float nf[NODE_IN];
  int v = blockIdx.x;
  int o = threadIdx.x;  // 64
  for (int i = o; i < NODE_IN; i += 64) nf[i] = node[(size_t)v * NODE_IN + i];
  __syncthreads();
  float acc = bp[o];
  for (int i = 0; i < NODE_IN; ++i) acc = fmaf(nf[i], Wp[i * OUTD + o], acc);
  h[(size_t)v * OUTD + o] = fmaxf(acc, 0.0f);
}

// f[e,k] = relu(edge[e,:] @ We1 + be1)   [E,12]@[12,128] fp32, stored f16
__global__ void edge_kernel(const float* __restrict__ ef,
                            const float* __restrict__ We1,
                            const float* __restrict__ be1,
                            _Float16* __restrict__ f) {
  __shared__ float es[EDGE_IN];
  int e = blockIdx.x;
  int k = threadIdx.x;  // 128
  if (k < EDGE_IN) es[k] = ef[(size_t)e * EDGE_IN + k];
  __syncthreads();
  float acc = be1[k];
  for (int j = 0; j < EDGE_IN; ++j) acc = fmaf(es[j], We1[j * EHID + k], acc);
  f[(size_t)e * EHID + k] = (_Float16)fmaxf(acc, 0.0f);
}

// SSTEP-contiguous + bank-swizzled B layout (f16) — unchanged from r7.
// Logical index: g = step*2048 + c*512 + l15*32 + quad*8 + j, step = i*4+s,
// value = f16(We2[k = s*32+quad*8+j][col = i*64 + c*16 + l15]).
// Stored at step*2048 + (eidx ^ ((eidx>>6 & 3) << 3))  (quad ^= l15[2:1]).
__global__ void w2r_kernel(const float* __restrict__ We2,
                           _Float16* __restrict__ w2s) {
  int g = blockIdx.x * 256 + threadIdx.x;  // < 524288 (logical index)
  int j = g & 7;
  int quad = (g >> 3) & 3;
  int l15 = (g >> 5) & 15;
  int c = (g >> 9) & 3;
  int step = g >> 11;     // 0..255
  int s = step & 3;
  int i = step >> 2;
  int k = s * 32 + quad * 8 + j;
  int col = i * 64 + c * 16 + l15;
  int eidx = g & 2047;
  int estore = eidx ^ (((eidx >> 6) & 3) << 3);
  w2s[((size_t)step << 11) | estore] = (_Float16)We2[(size_t)k * (OUTD * OUTD) + col];
}

#define GLOAD_LDS(gp, lp)                                                     \
  __builtin_amdgcn_global_load_lds(                                           \
      (const __attribute__((address_space(1))) void*)(gp),                    \
      (__attribute__((address_space(3))) void*)(lp), 16, 0, 0)

// Fused per-step message kernel (r7 shell + deep DMA pipeline):
// 4 waves/block, wave wv sums i in [16wv,16wv+16) for all 64 output cols.
// B streams global_load_lds -> per-wave 4-SLOT LDS ring (stage distance 3
// KSTEPs ~ 750cy >> DMA latency, so vmcnt(8) retires free) -> registers one
// KSTEP ahead (P/Q), so MFMAs never wait on ds_reads. Counted lgkmcnt
// before each re-stage guarantees the slot's prior ds_reads retired before
// the DMA write can land (race proven r6, fix proven r7). h-tile f16 with
// permuted layout: one ds_read_b64 per i, prefetched one i ahead.
__global__ __launch_bounds__(256, 2) void msg_kernel(
    const float* __restrict__ h,
    const _Float16* __restrict__ f,
    const _Float16* __restrict__ w2s,
    const int* __restrict__ src,
    const int* __restrict__ dst,
    const float* __restrict__ be2,
    float* __restrict__ agg) {
  // [0,8192): h16[64 i][64 pe] f16; [8192,73728): 4 per-wave 16KB rings.
  // Epilogue overlays [0,32768) as reduce scratch (all dead by then).
  __shared__ __align__(16) char smem_raw[73728];
  __shared__ int s_dst[64];

  _Float16* h16 = (_Float16*)smem_raw;  // elem (i, pe): pe = (e&15)*4 + (e>>4)

  const int tid = threadIdx.x;
  const int wv = tid >> 6;        // wave 0..3 -> i-subset [16wv,16wv+16)
  const int lane = tid & 63;
  const int quad = lane >> 4;
  const int l15 = lane & 15;
  const int e0 = blockIdx.x * 64;

  if (tid < 64) {
    int e = e0 + tid;
    s_dst[tid] = (e < En) ? dst[e] : -1;
  }
  // h gather: thread (e = tid&63, ib = tid>>6) writes i-block ib of edge e.
  // Permuted store pe(e) = (e&15)*4 + (e>>4): reader lane's 4 t-values
  // (e = t*16+l15) are contiguous 8B -> one ds_read_b64.
  {
    int e = tid & 63;
    int ib = tid >> 6;
    int eg = e0 + e;
    int sv = (eg < En) ? src[eg] : 0;
    const float4* hp = reinterpret_cast<const float4*>(h + (size_t)sv * OUTD + ib * 16);
    int pe = (e & 15) * 4 + (e >> 4);
#pragma unroll
    for (int c = 0; c < 4; ++c) {
      float4 v = hp[c];
      int i4 = ib * 16 + c * 4;
      h16[(i4 + 0) * 64 + pe] = (_Float16)v.x;
      h16[(i4 + 1) * 64 + pe] = (_Float16)v.y;
      h16[(i4 + 2) * 64 + pe] = (_Float16)v.z;
      h16[(i4 + 3) * 64 + pe] = (_Float16)v.w;
    }
  }
  __syncthreads();

  // A-fragments (f16): F rows for 4 row-tiles x 4 K-steps (i-invariant).
  half8 afr[4][4];
#pragma unroll
  for (int t = 0; t < 4; ++t) {
    int e = e0 + t * 16 + l15;
    if (e >= En) e = En - 1;  // clamped rows suppressed at scatter
    const _Float16* fr = f + (size_t)e * EHID + quad * 8;
#pragma unroll
    for (int s = 0; s < 4; ++s)
      afr[t][s] = *reinterpret_cast<const half8*>(fr + s * 32);
  }
  // drain afr loads so the K-loop's vmcnt counts ONLY ring DMAs
  asm volatile("s_waitcnt vmcnt(0)" ::: "memory");

  floatx4 acc[4][4];  // [row-tile t][col-stripe c]
  const floatx4 zero4 = (floatx4){0.f, 0.f, 0.f, 0.f};
#pragma unroll
  for (int t = 0; t < 4; ++t)
#pragma unroll
    for (int c = 0; c < 4; ++c) acc[t][c] = zero4;

  const int ibase = wv * 16;
  const int SBASE = ibase * 4;     // first w2s step of this wave
  const int SMAX = SBASE + 63;     // last valid step

  // per-wave private ring: 4 slots x 4KB
  char* ring = smem_raw + 8192 + wv * 16384;
  const char* w2b = (const char*)w2s;
  // swizzled per-lane byte offset within a 4KB chunk (stripe c adds 1024)
  const int roff = l15 * 64 + ((quad ^ ((l15 >> 1) & 3)) << 4);
  const char* sp0 = ring + roff;
  const char* sp1 = ring + 4096 + roff;
  const char* sp2 = ring + 8192 + roff;
  const char* sp3 = ring + 12288 + roff;

#define STAGE(GS, SLOT)                                                       \
  {                                                                           \
    const char* gp_ = w2b + (size_t)(GS) * 4096 + lane * 16;                  \
    char* lp_ = ring + (SLOT) * 4096;                                         \
    GLOAD_LDS(gp_, lp_);                                                      \
    GLOAD_LDS(gp_ + 1024, lp_ + 1024);                                        \
    GLOAD_LDS(gp_ + 2048, lp_ + 2048);                                        \
    GLOAD_LDS(gp_ + 3072, lp_ + 3072);                                        \
  }

#define VM8 asm volatile("s_waitcnt vmcnt(8)" ::: "memory")
#define VM0 asm volatile("s_waitcnt vmcnt(0)" ::: "memory")
#define LGKM0 asm volatile("s_waitcnt lgkmcnt(0)" ::: "memory")
#define LGKM4 asm volatile("s_waitcnt lgkmcnt(4)" ::: "memory")
#define LGKM5 asm volatile("s_waitcnt lgkmcnt(5)" ::: "memory")
#define SB __builtin_amdgcn_sched_barrier(0)

// KSTEP n (n = SBASE+ii*4+SS): (1) LW = counted lgkm wait: the staged slot's
// prior ds_reads (issued >=1 KSTEP ago) must be retired -> ~free; (2) stage
// step n+3 (clamped; tail reloads never consumed) into slot (SS+3)&3;
// (3) vmcnt(8): <=2 slots in flight => step n+1 (staged at n-2, ~750cy ago)
// landed -> free; (4) ds_read B(n+1) -> BRD (consumed NEXT KSTEP);
// (5) 16 MFMA on BMM = B(n), in registers since last KSTEP -> zero wait.
#define KSTEP(SS, BMM, BRD, STSL, RDP, GST, LW)                               \
  {                                                                           \
    LW;                                                                       \
    SB;                                                                       \
    int gs_ = (GST) > SMAX ? SMAX : (GST);                                    \
    STAGE(gs_, STSL);                                                         \
    VM8;                                                                      \
    BRD[0] = *reinterpret_cast<const half8*>(RDP);                            \
    BRD[1] = *reinterpret_cast<const half8*>(RDP + 1024);                     \
    BRD[2] = *reinterpret_cast<const half8*>(RDP + 2048);                     \
    BRD[3] = *reinterpret_cast<const half8*>(RDP + 3072);                     \
    __builtin_amdgcn_s_setprio(1);                                            \
    _Pragma("unroll") for (int t = 0; t < 4; ++t) {                           \
      half8 as = afr[t][SS] * hb[t];                                          \
      acc[t][0] = __builtin_amdgcn_mfma_f32_16x16x32_f16(as, BMM[0], acc[t][0], 0, 0, 0); \
      acc[t][1] = __builtin_amdgcn_mfma_f32_16x16x32_f16(as, BMM[1], acc[t][1], 0, 0, 0); \
      acc[t][2] = __builtin_amdgcn_mfma_f32_16x16x32_f16(as, BMM[2], acc[t][2], 0, 0, 0); \
      acc[t][3] = __builtin_amdgcn_mfma_f32_16x16x32_f16(as, BMM[3], acc[t][3], 0, 0, 0); \
    }                                                                         \
    __builtin_amdgcn_s_setprio(0);                                            \
  }

  // prologue: stage steps 0..2 into slots 0..2; read B(0) into P
  STAGE(SBASE, 0);
  STAGE(SBASE + 1, 1);
  STAGE(SBASE + 2, 2);
  VM8;  // 12 in flight -> wait until 8: step SBASE landed
  half8 P[4], Q[4];
  P[0] = *reinterpret_cast<const half8*>(sp0);
  P[1] = *reinterpret_cast<const half8*>(sp0 + 1024);
  P[2] = *reinterpret_cast<const half8*>(sp0 + 2048);
  P[3] = *reinterpret_cast<const half8*>(sp0 + 3072);

  // hv = 4 h-values (t=0..3) for current i, prefetched one i ahead
  half4 hv = *reinterpret_cast<const half4*>(h16 + ibase * 64 + l15 * 4);
  half4 hvn;

  for (int ii = 0; ii < 16; ++ii) {
    half8 hb[4];
#pragma unroll
    for (int t = 0; t < 4; ++t) {
      _Float16 hf = hv[t];
      hb[t] = (half8){hf, hf, hf, hf, hf, hf, hf, hf};
    }
    int gs = SBASE + ii * 4;
    KSTEP(0, P, Q, 3, sp1, gs + 3, LGKM4);
    {  // prefetch next i's h-values (drained by KSTEP1's LGKM5)
      int inx = (ii < 15) ? ii + 1 : 15;
      hvn = *reinterpret_cast<const half4*>(h16 + (ibase + inx) * 64 + l15 * 4);
    }
    KSTEP(1, Q, P, 0, sp2, gs + 4, LGKM5);
    KSTEP(2, P, Q, 1, sp3, gs + 5, LGKM4);
    KSTEP(3, Q, P, 2, sp0, gs + 6, LGKM4);
    hv = hvn;
  }

  // drain all in-flight DMAs/reads before LDS is repurposed
  VM0;
  LGKM0;

  // be2 contribution (exact 0 here, kept for generality): wave 0 owns all
  // cols pre-reduction, so add sum_i h[e,i]*be2[i*64+o] on wave 0 only.
  if (wv == 0) {
#pragma unroll
    for (int s = 0; s < 2; ++s) {
      half8 b2f[4];
#pragma unroll
      for (int c = 0; c < 4; ++c) {
        half8 v;
#pragma unroll
        for (int j = 0; j < 8; ++j)
          v[j] = (_Float16)be2[(s * 32 + quad * 8 + j) * 64 + c * 16 + l15];
        b2f[c] = v;
      }
#pragma unroll
      for (int t = 0; t < 4; ++t) {
        half8 ha;
#pragma unroll
        for (int j = 0; j < 8; ++j)
          ha[j] = h16[(s * 32 + quad * 8 + j) * 64 + l15 * 4 + t];
#pragma unroll
        for (int c = 0; c < 4; ++c)
          acc[t][c] = __builtin_amdgcn_mfma_f32_16x16x32_f16(ha, b2f[c], acc[t][c], 0, 0, 0);
      }
    }
  }

  // ---- two-stage cross-wave reduce over i-quarters, then scatter.
  floatx4* scv = reinterpret_cast<floatx4*>(smem_raw);

#define ST1(TG)                                                           \
  _Pragma("unroll") for (int c = 0; c < 4; ++c)                           \
      scv[wv * 512 + (((TG) & 1) * 4 + c) * 64 + lane] = acc[TG][c];
#define LD1(TK)                                                           \
  _Pragma("unroll") for (int c = 0; c < 4; ++c)                           \
      acc[TK][c] += scv[(wv ^ 1) * 512 + (((TK) & 1) * 4 + c) * 64 + lane];
#define ST2(TG)                                                           \
  _Pragma("unroll") for (int c = 0; c < 4; ++c)                           \
      scv[wv * 512 + c * 64 + lane] = acc[TG][c];
#define LD2(TK)                                                           \
  _Pragma("unroll") for (int c = 0; c < 4; ++c)                           \
      acc[TK][c] += scv[(wv ^ 2) * 512 + c * 64 + lane];
#define SCAT(TF)                                                          \
  {                                                                       \
    int rb = (TF) * 16 + quad * 4;                                        \
    _Pragma("unroll") for (int c = 0; c < 4; ++c) {                       \
      int col = c * 16 + l15;                                             \
      _Pragma("unroll") for (int r = 0; r < 4; ++r) {                     \
        int d = s_dst[rb + r];                                            \
        if (d >= 0) atomicAdd(&agg[(size_t)d * OUTD + col], acc[TF][c][r]); \
      }                                                                   \
    }                                                                     \
  }

  __syncthreads();  // h16 and rings dead from here; smem becomes scratch
  // stage 1: pairs (0,1),(2,3). even wave keeps rows t{0,1}, odd keeps t{2,3}
  if ((wv & 1) == 0) { ST1(2); ST1(3); } else { ST1(0); ST1(1); }
  __syncthreads();
  if ((wv & 1) == 0) { LD1(0); LD1(1); } else { LD1(2); LD1(3); }
  __syncthreads();
  // stage 2: pairs (0,2),(1,3). final tile: w0->t0, w2->t1, w1->t2, w3->t3
  if (wv == 0) { ST2(1); } else if (wv == 1) { ST2(3); }
  else if (wv == 2) { ST2(0); } else { ST2(2); }
  __syncthreads();
  if (wv == 0) { LD2(0); SCAT(0); }
  else if (wv == 1) { LD2(2); SCAT(2); }
  else if (wv == 2) { LD2(1); SCAT(1); }
  else { LD2(3); SCAT(3); }
}

// h_out = relu(agg + bias); re-zero agg; last step also writes fp32 d_out
__global__ void update_kernel(float* __restrict__ agg,
                              const float* __restrict__ bias,
                              float* __restrict__ hout,
                              float* __restrict__ dout, int last) {
  int g = blockIdx.x * 256 + threadIdx.x;
  if (g >= Vn * OUTD) return;
  float v = agg[g];
  agg[g] = 0.0f;
  float r = fmaxf(v + bias[g & 63], 0.0f);
  hout[g] = r;
  if (last) dout[g] = r;
}

extern "C" void kernel_launch(void* const* d_in, const int* in_sizes, int n_in,
                              void* d_out, int out_size, void* d_ws, size_t ws_size,
                              hipStream_t stream) {
  const float* node = (const float*)d_in[0];
  const float* edge = (const float*)d_in[1];
  const int* src = (const int*)d_in[2];
  const int* dst = (const int*)d_in[3];
  const float* Wp   = (const float*)d_in[4];
  const float* bp   = (const float*)d_in[5];
  const float* We1  = (const float*)d_in[6];
  const float* be1  = (const float*)d_in[7];
  const float* We2  = (const float*)d_in[8];
  const float* be2  = (const float*)d_in[9];
  const float* bias = (const float*)d_in[10];
  float* out = (float*)d_out;

  char* ws = (char*)d_ws;
  float* agg = (float*)(ws);                        // 6,400,000 B
  float* h_a = (float*)(ws + 6400000);              // 6,400,000 B
  float* h_b = (float*)(ws + 12800000);             // 6,400,000 B
  _Float16* f   = (_Float16*)(ws + 19200000);       // 25,600,000 B
  _Float16* w2s = (_Float16*)(ws + 44800000);       // 1,048,576 B

  hipMemsetAsync(agg, 0, (size_t)Vn * OUTD * sizeof(float), stream);
  proj_kernel<<<Vn, 64, 0, stream>>>(node, Wp, bp, h_a);
  edge_kernel<<<En, 128, 0, stream>>>(edge, We1, be1, f);
  w2r_kernel<<<(OUTD * OUTD * EHID) / 256, 256, 0, stream>>>(We2, w2s);

  float* hin = h_a;
  float* hout = h_b;
  for (int s = 0; s < NUM_STEPS; ++s) {
    msg_kernel<<<(En + 63) / 64, 256, 0, stream>>>(hin, f, w2s, src, dst, be2, agg);
    update_kernel<<<(Vn * OUTD + 255) / 256, 256, 0, stream>>>(
        agg, bias, hout, out, s == NUM_STEPS - 1);
    float* t = hin; hin = hout; hout = t;
  }
}

// Round 12
// 820.550 us; speedup vs baseline: 2.6439x; 1.0766x over previous
//
#include <hip/hip_runtime.h>
#include <hip/hip_bf16.h>

#define Vn 25000
#define En 100000
#define NODE_IN 74
#define EDGE_IN 12
#define OUTD 64
#define EHID 128
#define NUM_STEPS 6

typedef __attribute__((ext_vector_type(8))) _Float16 half8;
typedef __attribute__((ext_vector_type(2))) _Float16 half2v;
typedef __attribute__((ext_vector_type(4))) float floatx4;

// h[v,o] = relu(node[v,:] @ Wp + bp)   [V,74]@[74,64]  (all fp32)
__global__ void proj_kernel(const float* __restrict__ node,
                            const float* __restrict__ Wp,
                            const float* __restrict__ bp,
                            float* __restrict__ h) {
  __shared__ float nf[NODE_IN];
  int v = blockIdx.x;
  int o = threadIdx.x;  // 64
  for (int i = o; i < NODE_IN; i += 64) nf[i] = node[(size_t)v * NODE_IN + i];
  __syncthreads();
  float acc = bp[o];
  for (int i = 0; i < NODE_IN; ++i) acc = fmaf(nf[i], Wp[i * OUTD + o], acc);
  h[(size_t)v * OUTD + o] = fmaxf(acc, 0.0f);
}

// f[e,k] = relu(edge[e,:] @ We1 + be1)   [E,12]@[12,128] fp32, stored f16
__global__ void edge_kernel(const float* __restrict__ ef,
                            const float* __restrict__ We1,
                            const float* __restrict__ be1,
                            _Float16* __restrict__ f) {
  __shared__ float es[EDGE_IN];
  int e = blockIdx.x;
  int k = threadIdx.x;  // 128
  if (k < EDGE_IN) es[k] = ef[(size_t)e * EDGE_IN + k];
  __syncthreads();
  float acc = be1[k];
  for (int j = 0; j < EDGE_IN; ++j) acc = fmaf(es[j], We1[j * EHID + k], acc);
  f[(size_t)e * EHID + k] = (_Float16)fmaxf(acc, 0.0f);
}

// SSTEP-contiguous + bank-swizzled B layout (f16) — unchanged from r7.
// Logical index: g = step*2048 + c*512 + l15*32 + quad*8 + j, step = i*4+s,
// value = f16(We2[k = s*32+quad*8+j][col = i*64 + c*16 + l15]).
// Stored at step*2048 + (eidx ^ ((eidx>>6 & 3) << 3))  (quad ^= l15[2:1]).
__global__ void w2r_kernel(const float* __restrict__ We2,
                           _Float16* __restrict__ w2s) {
  int g = blockIdx.x * 256 + threadIdx.x;  // < 524288 (logical index)
  int j = g & 7;
  int quad = (g >> 3) & 3;
  int l15 = (g >> 5) & 15;
  int c = (g >> 9) & 3;
  int step = g >> 11;     // 0..255
  int s = step & 3;
  int i = step >> 2;
  int k = s * 32 + quad * 8 + j;
  int col = i * 64 + c * 16 + l15;
  int eidx = g & 2047;
  int estore = eidx ^ (((eidx >> 6) & 3) << 3);
  w2s[((size_t)step << 11) | estore] = (_Float16)We2[(size_t)k * (OUTD * OUTD) + col];
}

#define GLOAD_LDS(gp, lp)                                                     \
  __builtin_amdgcn_global_load_lds(                                           \
      (const __attribute__((address_space(1))) void*)(gp),                    \
      (__attribute__((address_space(3))) void*)(lp), 16, 0, 0)

// Fused per-step message kernel: BLOCK-SHARED B ring, edge-split waves.
// Block = 128 edges; wave wv owns edges [32wv, 32wv+32) over the FULL
// K = 8192 (no cross-wave reduce). All 4 waves traverse the same 256-step
// B sequence from ONE shared 4-slot ring: wave wv stages only stripe wv
// (1 DMA/KSTEP), all waves consume all 4 stripes -> B traffic cut 4x
// (1.6GB -> 0.4GB/step). Per KSTEP: vmcnt(2) (own stripe of step n landed,
// in-order retirement, dist-3) -> raw s_barrier (no counter drain!) ->
// ds_read slot n -> stage step n+3 -> 8 MFMA. Overwrite safety: each
// wave's reads of step n-1 are register-consumed by its MFMAs (compiler
// lgkm wait) BEFORE it reaches barrier n, so post-barrier stages can't
// race them. h is wave-private in LDS (no block-wide h dependency).
__global__ __launch_bounds__(256, 3) void msg_kernel(
    const float* __restrict__ h,
    const _Float16* __restrict__ f,
    const _Float16* __restrict__ w2s,
    const int* __restrict__ src,
    const int* __restrict__ dst,
    const float* __restrict__ be2,
    float* __restrict__ agg) {
  // [0,16384): per-wave h16 regions (4KB each): [64 i][32 pe] f16,
  //            pe(e) = (e&15)*2 + (e>>4)  -> reader's (t=0,1) pair is one b32.
  // [16384,32768): shared 4-slot B ring (4KB slots).
  __shared__ __align__(16) char smem_raw[32768];
  __shared__ int s_dst[128];

  const int tid = threadIdx.x;
  const int wv = tid >> 6;
  const int lane = tid & 63;
  const int quad = lane >> 4;
  const int l15 = lane & 15;
  const int e0 = blockIdx.x * 128;
  const int ew0 = e0 + wv * 32;   // this wave's first edge

  _Float16* h16w = (_Float16*)(smem_raw + wv * 4096);
  char* ring = smem_raw + 16384;

  // dst (wave-local 32 entries)
  if (lane < 32) {
    int eg = ew0 + lane;
    s_dst[wv * 32 + lane] = (eg < En) ? dst[eg] : -1;
  }
  // h gather (wave-private): lane l -> edge e_local = l&31, i-half = l>>5
  {
    int el = lane & 31;
    int ih = lane >> 5;
    int eg = ew0 + el;
    int sv = (eg < En) ? src[eg] : 0;
    const float4* hp = reinterpret_cast<const float4*>(h + (size_t)sv * OUTD + ih * 32);
    int pe = (el & 15) * 2 + (el >> 4);
#pragma unroll
    for (int c = 0; c < 8; ++c) {
      float4 v = hp[c];
      int i4 = ih * 32 + c * 4;
      h16w[(i4 + 0) * 32 + pe] = (_Float16)v.x;
      h16w[(i4 + 1) * 32 + pe] = (_Float16)v.y;
      h16w[(i4 + 2) * 32 + pe] = (_Float16)v.z;
      h16w[(i4 + 3) * 32 + pe] = (_Float16)v.w;
    }
  }

  // A-fragments: F rows for this wave's 2 row-tiles x 4 K-steps.
  half8 afr[2][4];
#pragma unroll
  for (int t = 0; t < 2; ++t) {
    int e = ew0 + t * 16 + l15;
    if (e >= En) e = En - 1;  // clamped rows suppressed at scatter
    const _Float16* fr = f + (size_t)e * EHID + quad * 8;
#pragma unroll
    for (int s = 0; s < 4; ++s)
      afr[t][s] = *reinterpret_cast<const half8*>(fr + s * 32);
  }

  floatx4 acc[2][4];  // [row-tile t][col-stripe c] — full K sum
  const floatx4 zero4 = (floatx4){0.f, 0.f, 0.f, 0.f};
#pragma unroll
  for (int t = 0; t < 2; ++t)
#pragma unroll
    for (int c = 0; c < 4; ++c) acc[t][c] = zero4;

  const char* w2b = (const char*)w2s;
  // swizzled per-lane byte offset within a 4KB chunk (stripe c adds 1024)
  const int roff = l15 * 64 + ((quad ^ ((l15 >> 1) & 3)) << 4);
  const char* sp0 = ring + roff;
  const char* sp1 = ring + 4096 + roff;
  const char* sp2 = ring + 8192 + roff;
  const char* sp3 = ring + 12288 + roff;

// this wave stages ONLY stripe wv of step GS into slot SLOT (1 DMA inst)
#define STAGE1(GS, SLOT)                                                      \
  {                                                                           \
    const char* gp_ = w2b + (size_t)(GS) * 4096 + (wv << 10) + lane * 16;     \
    char* lp_ = ring + (SLOT) * 4096 + (wv << 10);                            \
    GLOAD_LDS(gp_, lp_);                                                      \
  }

  // drain ALL prologue vmem (h gather, afr) so loop vmcnt counts only DMAs
  asm volatile("s_waitcnt vmcnt(0)" ::: "memory");

  // prologue: stage steps 0..2 into slots 0..2 (1 stripe per wave each)
  STAGE1(0, 0);
  STAGE1(1, 1);
  STAGE1(2, 2);

  half2v hv = *reinterpret_cast<const half2v*>(h16w + l15 * 2);  // i = 0
  half2v hvn;

// KSTEP n (static SS = n&3): vmcnt(2) drains this wave's stripe of step n
// (issued at n-3; outstanding n-2,n-1 remain); barrier => ALL stripes of
// step n landed and all waves' reads of step n-1 retired; read slot SS;
// stage step n+3 (clamped; tail duplicates land in never-again-read slots)
// into slot (SS+3)&3; 8 MFMA on the fresh reads (compiler lgkm wait).
#define KSTEP(SS, SPS, GST)                                                   \
  {                                                                           \
    asm volatile("s_waitcnt vmcnt(2)" ::: "memory");                          \
    asm volatile("s_barrier" ::: "memory");                                   \
    half8 B0 = *reinterpret_cast<const half8*>(SPS);                          \
    half8 B1 = *reinterpret_cast<const half8*>(SPS + 1024);                   \
    half8 B2 = *reinterpret_cast<const half8*>(SPS + 2048);                   \
    half8 B3 = *reinterpret_cast<const half8*>(SPS + 3072);                   \
    int gs_ = (GST) > 255 ? 255 : (GST);                                      \
    STAGE1(gs_, ((SS) + 3) & 3);                                              \
    __builtin_amdgcn_s_setprio(1);                                            \
    _Pragma("unroll") for (int t = 0; t < 2; ++t) {                           \
      half8 as = afr[t][SS] * hb[t];                                          \
      acc[t][0] = __builtin_amdgcn_mfma_f32_16x16x32_f16(as, B0, acc[t][0], 0, 0, 0); \
      acc[t][1] = __builtin_amdgcn_mfma_f32_16x16x32_f16(as, B1, acc[t][1], 0, 0, 0); \
      acc[t][2] = __builtin_amdgcn_mfma_f32_16x16x32_f16(as, B2, acc[t][2], 0, 0, 0); \
      acc[t][3] = __builtin_amdgcn_mfma_f32_16x16x32_f16(as, B3, acc[t][3], 0, 0, 0); \
    }                                                                         \
    __builtin_amdgcn_s_setprio(0);                                            \
  }

  for (int i = 0; i < 64; ++i) {
    half8 hb[2];
#pragma unroll
    for (int t = 0; t < 2; ++t) {
      _Float16 hf = hv[t];
      hb[t] = (half8){hf, hf, hf, hf, hf, hf, hf, hf};
    }
    int gs = i * 4;
    KSTEP(0, sp0, gs + 3);
    {  // prefetch next i's h pair (wave-local; compiler orders via lgkm)
      int inx = (i < 63) ? i + 1 : 63;
      hvn = *reinterpret_cast<const half2v*>(h16w + inx * 32 + l15 * 2);
    }
    KSTEP(1, sp1, gs + 4);
    KSTEP(2, sp2, gs + 5);
    KSTEP(3, sp3, gs + 6);
    hv = hvn;
  }

  // drain leftover tail DMAs before kernel teardown
  asm volatile("s_waitcnt vmcnt(0)" ::: "memory");

  // be2 contribution (exact 0 here, kept for generality): each wave owns its
  // edges' full i-range -> add sum_i h[e,i]*be2[i*64+o] once per edge row.
  {
#pragma unroll
    for (int s = 0; s < 2; ++s) {
      half8 b2f[4];
#pragma unroll
      for (int c = 0; c < 4; ++c) {
        half8 v;
#pragma unroll
        for (int j = 0; j < 8; ++j)
          v[j] = (_Float16)be2[(s * 32 + quad * 8 + j) * 64 + c * 16 + l15];
        b2f[c] = v;
      }
#pragma unroll
      for (int t = 0; t < 2; ++t) {
        half8 ha;
#pragma unroll
        for (int j = 0; j < 8; ++j)
          ha[j] = h16w[(s * 32 + quad * 8 + j) * 32 + l15 * 2 + t];
#pragma unroll
        for (int c = 0; c < 4; ++c)
          acc[t][c] = __builtin_amdgcn_mfma_f32_16x16x32_f16(ha, b2f[c], acc[t][c], 0, 0, 0);
      }
    }
  }

  // direct scatter (no reduce): C/D layout col=lane&15, row=quad*4+reg
#pragma unroll
  for (int t = 0; t < 2; ++t) {
    int rb = wv * 32 + t * 16 + quad * 4;
#pragma unroll
    for (int c = 0; c < 4; ++c) {
      int col = c * 16 + l15;
#pragma unroll
      for (int r = 0; r < 4; ++r) {
        int d = s_dst[rb + r];
        if (d >= 0) atomicAdd(&agg[(size_t)d * OUTD + col], acc[t][c][r]);
      }
    }
  }
}

// h_out = relu(agg + bias); re-zero agg; last step also writes fp32 d_out
__global__ void update_kernel(float* __restrict__ agg,
                              const float* __restrict__ bias,
                              float* __restrict__ hout,
                              float* __restrict__ dout, int last) {
  int g = blockIdx.x * 256 + threadIdx.x;
  if (g >= Vn * OUTD) return;
  float v = agg[g];
  agg[g] = 0.0f;
  float r = fmaxf(v + bias[g & 63], 0.0f);
  hout[g] = r;
  if (last) dout[g] = r;
}

extern "C" void kernel_launch(void* const* d_in, const int* in_sizes, int n_in,
                              void* d_out, int out_size, void* d_ws, size_t ws_size,
                              hipStream_t stream) {
  const float* node = (const float*)d_in[0];
  const float* edge = (const float*)d_in[1];
  const int* src = (const int*)d_in[2];
  const int* dst = (const int*)d_in[3];
  const float* Wp   = (const float*)d_in[4];
  const float* bp   = (const float*)d_in[5];
  const float* We1  = (const float*)d_in[6];
  const float* be1  = (const float*)d_in[7];
  const float* We2  = (const float*)d_in[8];
  const float* be2  = (const float*)d_in[9];
  const float* bias = (const float*)d_in[10];
  float* out = (float*)d_out;

  char* ws = (char*)d_ws;
  float* agg = (float*)(ws);                        // 6,400,000 B
  float* h_a = (float*)(ws + 6400000);              // 6,400,000 B
  float* h_b = (float*)(ws + 12800000);             // 6,400,000 B
  _Float16* f   = (_Float16*)(ws + 19200000);       // 25,600,000 B
  _Float16* w2s = (_Float16*)(ws + 44800000);       // 1,048,576 B

  hipMemsetAsync(agg, 0, (size_t)Vn * OUTD * sizeof(float), stream);
  proj_kernel<<<Vn, 64, 0, stream>>>(node, Wp, bp, h_a);
  edge_kernel<<<En, 128, 0, stream>>>(edge, We1, be1, f);
  w2r_kernel<<<(OUTD * OUTD * EHID) / 256, 256, 0, stream>>>(We2, w2s);

  float* hin = h_a;
  float* hout = h_b;
  const int nblocks = (En + 127) / 128;  // 782
  for (int s = 0; s < NUM_STEPS; ++s) {
    msg_kernel<<<nblocks, 256, 0, stream>>>(hin, f, w2s, src, dst, be2, agg);
    update_kernel<<<(Vn * OUTD + 255) / 256, 256, 0, stream>>>(
        agg, bias, hout, out, s == NUM_STEPS - 1);
    float* t = hin; hin = hout; hout = t;
  }
}